// Round 12
// baseline (440.281 us; speedup 1.0000x reference)
//
#include <hip/hip_runtime.h>

// ---------------- problem constants ----------------
#define NCLS   21
#define HI     512
#define WI     512
#define PH     171                 // pooled H=W: floor((512+2-3)/3)+1
#define PLANE  (PH*PH)             // 29241
#define NH     169                 // PH - (RADIUS-1)
#define MPTS   (NH*NH)             // 28561
#define NBATCH 4
#define NC     (NBATCH*NCLS)       // 84
#define ALPHA  5e-4f
#define SPLIT  8                   // m-range splits per (n,c) in cov kernel

// ---------------- workspace layout (bytes) ----------------
#define OFF_BCE    0                         // double[64]
#define OFF_VALID  512                       // double[64]
#define OFF_MEANS  1024                      // float[NC][18]  (crop sums: 9 la, 9 pr)
#define OFF_COV    7104                      // float[NC][171] (ll45 | pp45 | lp81)
#define ZERO_BYTES (OFF_COV + NC*171*4)      // 64560
#define OFF_LA8    65536                     // uchar[NC][PLANE]  (pooled one-hot, binary)
#define OFF_PR     (65536 + ((NC*PLANE + 255)/256)*256)   // float[NC][PLANE]

// triangular index helpers (valid only with compile-time-constant args after unroll)
#define IDX(i,j) ((i)*((i)+1)/2 + (j))                     // lower tri, i>=j
#define KU(d,e)  (9*(d) - ((d)*((d)-1))/2 + ((e)-(d)))     // upper-order tri, d<=e

__device__ __forceinline__ float wave_red(float v) {
#pragma unroll
    for (int off = 32; off; off >>= 1) v += __shfl_down(v, off, 64);
    return v;
}

// =====================================================================
// Kernel 1: fused BCE + sigmoid + 3x3/s3 max-pool + crop-sum partials.
// R4 profile: VALUBusy 102%, HBM 8% -> libm expf/log1pf/fdiv dominated
// (~400 lane-ops/elem). Fix: log1p(exp(-|x|)) == log(1+t) with t=__expf,
// reciprocal via v_rcp_f32, log via v_log_f32 (u in (1,2] -> well
// conditioned). ~20 ops/elem. Inputs are L3-resident (92 MB < 256 MB),
// so this kernel is VALU-bound outright; floor ~8 us. (R4: VGPR=16 ->
// occupancy was never the limit; pure op-count was.)
// =====================================================================
__global__ __launch_bounds__(256) void pool_bce_kernel(
    const float* __restrict__ logits, const int* __restrict__ labels,
    unsigned char* __restrict__ la_pool, float* __restrict__ pr_pool,
    float* __restrict__ meansums, double* __restrict__ bce_part,
    double* __restrict__ valid_part)
{
    const int c = blockIdx.y, n = blockIdx.z;
    const int pos = blockIdx.x * 256 + threadIdx.x;
    const int plane = n * NCLS + c;

    float bce_acc = 0.f, cnt = 0.f;
    float sl[9], sp[9];
#pragma unroll
    for (int d = 0; d < 9; ++d) { sl[d] = 0.f; sp[d] = 0.f; }

    if (pos < PLANE) {
        const int oh = pos / PH, ow = pos - oh * PH;
        const float* lg = logits + (size_t)plane * (HI * WI);
        const int*   lb = labels + (size_t)n * (HI * WI);
        float mx_la = -1.f, mx_pr = -1.f;   // all candidates >= 0, so -1 acts as -inf
        const int r0 = 3 * oh - 1, c0 = 3 * ow - 1;
        // only oh==0 / ow==0 can go out of bounds (r0=-1 / c0=-1); high side
        // never exceeds 511 (3*170+1=511).
#pragma unroll
        for (int dy = 0; dy < 3; ++dy) {
            const int r = r0 + dy;
            if (r < 0) continue;
#pragma unroll
            for (int dx = 0; dx < 3; ++dx) {
                const int cc = c0 + dx;
                if (cc < 0) continue;
                const float x   = lg[r * WI + cc];
                const int  lab  = lb[r * WI + cc];
                const bool m    = (lab < NCLS);
                const float o   = (m && lab == c) ? 1.f : 0.f;
                const float t   = __expf(-fabsf(x));       // v_exp_f32 path
                const float u   = 1.f + t;                 // in (1,2]
                const float rc  = __builtin_amdgcn_rcpf(u);// ~1ulp reciprocal
                const float lgu = __logf(u);               // = log1p(t)
                const float sig = (x >= 0.f) ? rc : t * rc;
                if (m) bce_acc += fmaxf(x, 0.f) - x * o + lgu;
                if (m && c == 0) cnt += 1.f;
                mx_la = fmaxf(mx_la, o);
                mx_pr = fmaxf(mx_pr, (m ? sig : 0.f) + 1e-6f);
            }
        }
        la_pool[(size_t)plane * PLANE + pos] = (unsigned char)mx_la;
        pr_pool[(size_t)plane * PLANE + pos] = mx_pr;
        // crop-sum contributions: pooled (oh,ow) lies in crop (y,x) iff shifted idx in [0,NH)
#pragma unroll
        for (int y = 0; y < 3; ++y)
#pragma unroll
            for (int x = 0; x < 3; ++x) {
                const int d = y * 3 + x;
                if (oh >= y && oh <= y + NH - 1 && ow >= x && ow <= x + NH - 1) {
                    sl[d] += mx_la; sp[d] += mx_pr;
                }
            }
    }

    // block reduce 18 crop sums + bce + valid-count
    __shared__ float red[4][20];
    const int lane = threadIdx.x & 63, wid = threadIdx.x >> 6;
    float vals[20];
#pragma unroll
    for (int d = 0; d < 9; ++d) { vals[d] = sl[d]; vals[9 + d] = sp[d]; }
    vals[18] = bce_acc; vals[19] = cnt;
#pragma unroll
    for (int q = 0; q < 20; ++q) {
        const float v = wave_red(vals[q]);
        if (lane == 0) red[wid][q] = v;
    }
    __syncthreads();
    if (threadIdx.x < 20) {
        const float v = red[0][threadIdx.x] + red[1][threadIdx.x]
                      + red[2][threadIdx.x] + red[3][threadIdx.x];
        if (threadIdx.x < 18) {
            atomicAdd(meansums + plane * 18 + threadIdx.x, v);
        } else if (threadIdx.x == 18) {
            const int bid = (blockIdx.z * gridDim.y + blockIdx.y) * gridDim.x + blockIdx.x;
            atomicAdd(bce_part + (bid & 63), (double)v);
        } else if (blockIdx.y == 0) {
            const int bid = blockIdx.z * gridDim.x + blockIdx.x;
            atomicAdd(valid_part + (bid & 63), (double)v);
        }
    }
}

// =====================================================================
// Kernel 2: centered covariance sums per (n,c), WAVE-SPLIT outputs.
// R4 suspicion: 171 acc/thread => ~220+ VGPR => 1 wave/SIMD (+spill?).
// Now each of the block's 4 waves owns a disjoint output subset
// (<=45 acc, ~85 VGPR total) and iterates the same point range; inputs
// are L1/L2-resident so duplicated reads are cheap.
//   wave0: ll[45]  wave1: pp[45]  wave2: lp d=0..3  wave3: lp d=4..8
// =====================================================================
__global__ __launch_bounds__(256, 4) void cov_kernel(
    const unsigned char* __restrict__ la_pool, const float* __restrict__ pr_pool,
    const float* __restrict__ meansums, float* __restrict__ covbuf)
{
    const int nc = blockIdx.x / SPLIT, s = blockIdx.x % SPLIT;
    const int lane = threadIdx.x & 63, wid = threadIdx.x >> 6;
    const unsigned char* la = la_pool + (size_t)nc * PLANE;
    const float*         pr = pr_pool + (size_t)nc * PLANE;

    float ml[9], mp[9];
    const float invM = 1.f / (float)MPTS;
#pragma unroll
    for (int d = 0; d < 9; ++d) {
        ml[d] = meansums[nc * 18 + d]     * invM;
        mp[d] = meansums[nc * 18 + 9 + d] * invM;
    }

    float acc[45];
#pragma unroll
    for (int k = 0; k < 45; ++k) acc[k] = 0.f;

    for (int m = s * 64 + lane; m < MPTS; m += 64 * SPLIT) {
        const int i = m / NH;
        const int base = m + 2 * i;          // i*PH + (m - i*NH), PH-NH==2
        if (wid == 0) {
            float lv[9];
#pragma unroll
            for (int y = 0; y < 3; ++y)
#pragma unroll
                for (int x = 0; x < 3; ++x)
                    lv[y * 3 + x] = (float)la[base + y * PH + x] - ml[y * 3 + x];
            int k = 0;
#pragma unroll
            for (int d = 0; d < 9; ++d)
#pragma unroll
                for (int e = d; e < 9; ++e) { acc[k++] += lv[d] * lv[e]; }
        } else if (wid == 1) {
            float pv[9];
#pragma unroll
            for (int y = 0; y < 3; ++y)
#pragma unroll
                for (int x = 0; x < 3; ++x)
                    pv[y * 3 + x] = pr[base + y * PH + x] - mp[y * 3 + x];
            int k = 0;
#pragma unroll
            for (int d = 0; d < 9; ++d)
#pragma unroll
                for (int e = d; e < 9; ++e) { acc[k++] += pv[d] * pv[e]; }
        } else if (wid == 2) {
            float lv[4], pv[9];
#pragma unroll
            for (int d = 0; d < 4; ++d)
                lv[d] = (float)la[base + (d / 3) * PH + (d % 3)] - ml[d];
#pragma unroll
            for (int y = 0; y < 3; ++y)
#pragma unroll
                for (int x = 0; x < 3; ++x)
                    pv[y * 3 + x] = pr[base + y * PH + x] - mp[y * 3 + x];
#pragma unroll
            for (int d = 0; d < 4; ++d)
#pragma unroll
                for (int e = 0; e < 9; ++e) acc[d * 9 + e] += lv[d] * pv[e];
        } else {
            float lv[5], pv[9];
#pragma unroll
            for (int d = 4; d < 9; ++d)
                lv[d - 4] = (float)la[base + (d / 3) * PH + (d % 3)] - ml[d];
#pragma unroll
            for (int y = 0; y < 3; ++y)
#pragma unroll
                for (int x = 0; x < 3; ++x)
                    pv[y * 3 + x] = pr[base + y * PH + x] - mp[y * 3 + x];
#pragma unroll
            for (int d = 0; d < 5; ++d)
#pragma unroll
                for (int e = 0; e < 9; ++e) acc[d * 9 + e] += lv[d] * pv[e];
        }
    }

    // per-wave shuffle reduce + one atomic per output from lane 0
    const int nacc = (wid == 2) ? 36 : 45;
    const int obase = (wid == 0) ? 0 : (wid == 1) ? 45 : (wid == 2) ? 90 : 126;
#pragma unroll
    for (int k = 0; k < 45; ++k) {
        if (k >= nacc) break;
        const float v = wave_red(acc[k]);
        if (lane == 0) atomicAdd(covbuf + nc * 171 + obase + k, v);
    }
}

// =====================================================================
// Kernel 3: per-(n,c) 9x9 SPD math, one thread each (fully unrolled so
// all triangular arrays stay in registers), block reduce, final combine.
//   P = pp + aI = L L^T ;  Y = L^{-1} B^T ;  V = ll - Y^T Y + aI
//   rmi = 0.5 * logdet(V) = sum(log(chol(V).diag))
// =====================================================================
__global__ __launch_bounds__(128, 1) void final_kernel(
    const float* __restrict__ covbuf, const double* __restrict__ bce_part,
    const double* __restrict__ valid_part, float* __restrict__ out)
{
    const int t = threadIdx.x;
    float rmi = 0.f;
    if (t < NC) {
        const float* cb = covbuf + t * 171;

        // --- Cholesky of P = pp + alpha*I (pp stored upper-order at cb[45..89]) ---
        float L[45], dinv[9];
#pragma unroll
        for (int k = 0; k < 9; ++k) {
            float s = cb[45 + KU(k, k)] + ALPHA;
#pragma unroll
            for (int p = 0; p < k; ++p) s -= L[IDX(k, p)] * L[IDX(k, p)];
            const float dk = sqrtf(s);
            L[IDX(k, k)] = dk;
            dinv[k] = 1.f / dk;
#pragma unroll
            for (int i = k + 1; i < 9; ++i) {
                float t2 = cb[45 + KU(k, i)];
#pragma unroll
                for (int p = 0; p < k; ++p) t2 -= L[IDX(i, p)] * L[IDX(k, p)];
                L[IDX(i, k)] = t2 * dinv[k];
            }
        }

        // --- forward substitution: Y = L^{-1} B^T, B[d][e]=lp[d*9+e] at cb[90..170] ---
        float Yv[81];
#pragma unroll
        for (int i = 0; i < 9; ++i)
#pragma unroll
            for (int j = 0; j < 9; ++j) Yv[i * 9 + j] = cb[90 + j * 9 + i];  // B^T
#pragma unroll
        for (int i = 0; i < 9; ++i)
#pragma unroll
            for (int j = 0; j < 9; ++j) {
                float t2 = Yv[i * 9 + j];
#pragma unroll
                for (int p = 0; p < i; ++p) t2 -= L[IDX(i, p)] * Yv[p * 9 + j];
                Yv[i * 9 + j] = t2 * dinv[i];
            }

        // --- V = ll - Y^T Y (upper-order), then Cholesky + logdet ---
        float V[45];
#pragma unroll
        for (int d = 0; d < 9; ++d)
#pragma unroll
            for (int e = d; e < 9; ++e) {
                float s = cb[KU(d, e)];
#pragma unroll
                for (int i = 0; i < 9; ++i) s -= Yv[i * 9 + d] * Yv[i * 9 + e];
                V[KU(d, e)] = s;
            }
        float M2[45];
        float rmi_acc = 0.f;
#pragma unroll
        for (int k = 0; k < 9; ++k) {
            float s = V[KU(k, k)] + ALPHA;
#pragma unroll
            for (int p = 0; p < k; ++p) s -= M2[IDX(k, p)] * M2[IDX(k, p)];
            const float dk = sqrtf(s);
            M2[IDX(k, k)] = dk;
            rmi_acc += logf(dk);
            const float di = 1.f / dk;
#pragma unroll
            for (int i = k + 1; i < 9; ++i) {
                float t2 = V[KU(k, i)];
#pragma unroll
                for (int p = 0; p < k; ++p) t2 -= M2[IDX(i, p)] * M2[IDX(k, p)];
                M2[IDX(i, k)] = t2 * di;
            }
        }
        rmi = rmi_acc;  // = 0.5 * logdet
    }

    __shared__ float red[128];
    red[t] = rmi;
    __syncthreads();
#pragma unroll
    for (int off = 64; off >= 1; off >>= 1) {
        if (t < off) red[t] += red[t + off];
        __syncthreads();
    }
    if (t == 0) {
        double b = 0.0, v = 0.0;
        for (int k = 0; k < 64; ++k) { b += bce_part[k]; v += valid_part[k]; }
        const float bce_loss = (float)(b / (v + 1.0));
        const float rmi_loss = red[0] / (float)(NBATCH * 9);   // mean over N, /HALF_D, sum over C
        out[0] = 0.5f * bce_loss + 0.5f * rmi_loss;
    }
}

// =====================================================================
extern "C" void kernel_launch(void* const* d_in, const int* in_sizes, int n_in,
                              void* d_out, int out_size, void* d_ws, size_t ws_size,
                              hipStream_t stream)
{
    const float* logits = (const float*)d_in[0];
    const int*   labels = (const int*)d_in[1];
    char* ws = (char*)d_ws;

    double*        bce_part   = (double*)(ws + OFF_BCE);
    double*        valid_part = (double*)(ws + OFF_VALID);
    float*         meansums   = (float*)(ws + OFF_MEANS);
    float*         covbuf     = (float*)(ws + OFF_COV);
    unsigned char* la_pool    = (unsigned char*)(ws + OFF_LA8);
    float*         pr_pool    = (float*)(ws + OFF_PR);

    hipMemsetAsync(ws, 0, ZERO_BYTES, stream);

    dim3 g1((PLANE + 255) / 256, NCLS, NBATCH);
    pool_bce_kernel<<<g1, 256, 0, stream>>>(logits, labels, la_pool, pr_pool,
                                            meansums, bce_part, valid_part);
    cov_kernel<<<NC * SPLIT, 256, 0, stream>>>(la_pool, pr_pool, meansums, covbuf);
    final_kernel<<<1, 128, 0, stream>>>(covbuf, bce_part, valid_part, (float*)d_out);
}

// Round 13
// 262.770 us; speedup vs baseline: 1.6755x; 1.6755x over previous
//
#include <hip/hip_runtime.h>

// ---------------- problem constants ----------------
#define NCLS   21
#define HI     512
#define WI     512
#define PH     171                 // pooled H=W: floor((512+2-3)/3)+1
#define PLANE  (PH*PH)             // 29241
#define NH     169                 // PH - (RADIUS-1)
#define MPTS   (NH*NH)             // 28561
#define NBATCH 4
#define NC     (NBATCH*NCLS)       // 84
#define ALPHA  5e-4f
#define SPLIT  8                   // m-range splits per (n,c) in cov kernel

// ---------------- workspace layout (bytes) ----------------
#define OFF_BCE    0                         // double[64]
#define OFF_VALID  512                       // double[64]
#define OFF_MEANS  1024                      // float[NC][18]  (crop sums: 9 la, 9 pr)
#define OFF_COV    7104                      // float[NC][171] (ll45 | pp45 | lp81)
#define ZERO_BYTES (OFF_COV + NC*171*4)      // 64560
#define OFF_LA8    65536                     // uchar[NC][PLANE]  (pooled one-hot, binary)
#define OFF_PR     (65536 + ((NC*PLANE + 255)/256)*256)   // float[NC][PLANE]

// triangular index helpers (valid only with compile-time-constant args after unroll)
#define IDX(i,j) ((i)*((i)+1)/2 + (j))                     // lower tri, i>=j
#define KU(d,e)  (9*(d) - ((d)*((d)-1))/2 + ((e)-(d)))     // upper-order tri, d<=e

__device__ __forceinline__ float wave_red(float v) {
#pragma unroll
    for (int off = 32; off; off >>= 1) v += __shfl_down(v, off, 64);
    return v;
}

// =====================================================================
// Kernel 1: fused BCE + sigmoid + 3x3/s3 max-pool + crop-sum partials.
// R4 profile: VALUBusy 102%, HBM 8% -> libm expf/log1pf/fdiv dominated
// (~400 lane-ops/elem). Fix: log1p(exp(-|x|)) == log(1+t) with t=__expf,
// reciprocal via v_rcp_f32, log via v_log_f32 (u in (1,2] -> well
// conditioned). ~20 ops/elem. Inputs are L3-resident (92 MB < 256 MB),
// so this kernel is VALU-bound outright; floor ~8 us. (R4: VGPR=16 ->
// occupancy was never the limit; pure op-count was.)
// =====================================================================
__global__ __launch_bounds__(256) void pool_bce_kernel(
    const float* __restrict__ logits, const int* __restrict__ labels,
    unsigned char* __restrict__ la_pool, float* __restrict__ pr_pool,
    float* __restrict__ meansums, double* __restrict__ bce_part,
    double* __restrict__ valid_part)
{
    const int c = blockIdx.y, n = blockIdx.z;
    const int pos = blockIdx.x * 256 + threadIdx.x;
    const int plane = n * NCLS + c;

    float bce_acc = 0.f, cnt = 0.f;
    float sl[9], sp[9];
#pragma unroll
    for (int d = 0; d < 9; ++d) { sl[d] = 0.f; sp[d] = 0.f; }

    if (pos < PLANE) {
        const int oh = pos / PH, ow = pos - oh * PH;
        const float* lg = logits + (size_t)plane * (HI * WI);
        const int*   lb = labels + (size_t)n * (HI * WI);
        float mx_la = -1.f, mx_pr = -1.f;   // all candidates >= 0, so -1 acts as -inf
        const int r0 = 3 * oh - 1, c0 = 3 * ow - 1;
        // only oh==0 / ow==0 can go out of bounds (r0=-1 / c0=-1); high side
        // never exceeds 511 (3*170+1=511).
#pragma unroll
        for (int dy = 0; dy < 3; ++dy) {
            const int r = r0 + dy;
            if (r < 0) continue;
#pragma unroll
            for (int dx = 0; dx < 3; ++dx) {
                const int cc = c0 + dx;
                if (cc < 0) continue;
                const float x   = lg[r * WI + cc];
                const int  lab  = lb[r * WI + cc];
                const bool m    = (lab < NCLS);
                const float o   = (m && lab == c) ? 1.f : 0.f;
                const float t   = __expf(-fabsf(x));       // v_exp_f32 path
                const float u   = 1.f + t;                 // in (1,2]
                const float rc  = __builtin_amdgcn_rcpf(u);// ~1ulp reciprocal
                const float lgu = __logf(u);               // = log1p(t)
                const float sig = (x >= 0.f) ? rc : t * rc;
                if (m) bce_acc += fmaxf(x, 0.f) - x * o + lgu;
                if (m && c == 0) cnt += 1.f;
                mx_la = fmaxf(mx_la, o);
                mx_pr = fmaxf(mx_pr, (m ? sig : 0.f) + 1e-6f);
            }
        }
        la_pool[(size_t)plane * PLANE + pos] = (unsigned char)mx_la;
        pr_pool[(size_t)plane * PLANE + pos] = mx_pr;
        // crop-sum contributions: pooled (oh,ow) lies in crop (y,x) iff shifted idx in [0,NH)
#pragma unroll
        for (int y = 0; y < 3; ++y)
#pragma unroll
            for (int x = 0; x < 3; ++x) {
                const int d = y * 3 + x;
                if (oh >= y && oh <= y + NH - 1 && ow >= x && ow <= x + NH - 1) {
                    sl[d] += mx_la; sp[d] += mx_pr;
                }
            }
    }

    // block reduce 18 crop sums + bce + valid-count
    __shared__ float red[4][20];
    const int lane = threadIdx.x & 63, wid = threadIdx.x >> 6;
    float vals[20];
#pragma unroll
    for (int d = 0; d < 9; ++d) { vals[d] = sl[d]; vals[9 + d] = sp[d]; }
    vals[18] = bce_acc; vals[19] = cnt;
#pragma unroll
    for (int q = 0; q < 20; ++q) {
        const float v = wave_red(vals[q]);
        if (lane == 0) red[wid][q] = v;
    }
    __syncthreads();
    if (threadIdx.x < 20) {
        const float v = red[0][threadIdx.x] + red[1][threadIdx.x]
                      + red[2][threadIdx.x] + red[3][threadIdx.x];
        if (threadIdx.x < 18) {
            atomicAdd(meansums + plane * 18 + threadIdx.x, v);
        } else if (threadIdx.x == 18) {
            const int bid = (blockIdx.z * gridDim.y + blockIdx.y) * gridDim.x + blockIdx.x;
            atomicAdd(bce_part + (bid & 63), (double)v);
        } else if (blockIdx.y == 0) {
            const int bid = blockIdx.z * gridDim.x + blockIdx.x;
            atomicAdd(valid_part + (bid & 63), (double)v);
        }
    }
}

// =====================================================================
// Kernel 2: centered covariance sums per (n,c), WAVE-SPLIT outputs.
// R12 post-mortem: the reduction loop's runtime `break` (nacc depends on
// wid) defeated unrolling -> acc[k] runtime-indexed -> the whole acc[45]
// array went to SCRATCH (VGPR=60, WRITE_SIZE=620MB, 262us, VALUBusy 8%).
// Fix: compile-time trip count (always 45 wave_reds), mask the ATOMIC,
// not the loop. All acc indices static -> registers.
//   wave0: ll[45]  wave1: pp[45]  wave2: lp d=0..3 (36)  wave3: lp d=4..8
// =====================================================================
__global__ __launch_bounds__(256, 4) void cov_kernel(
    const unsigned char* __restrict__ la_pool, const float* __restrict__ pr_pool,
    const float* __restrict__ meansums, float* __restrict__ covbuf)
{
    const int nc = blockIdx.x / SPLIT, s = blockIdx.x % SPLIT;
    const int lane = threadIdx.x & 63, wid = threadIdx.x >> 6;
    const unsigned char* la = la_pool + (size_t)nc * PLANE;
    const float*         pr = pr_pool + (size_t)nc * PLANE;

    float ml[9], mp[9];
    const float invM = 1.f / (float)MPTS;
#pragma unroll
    for (int d = 0; d < 9; ++d) {
        ml[d] = meansums[nc * 18 + d]     * invM;
        mp[d] = meansums[nc * 18 + 9 + d] * invM;
    }

    float acc[45];
#pragma unroll
    for (int k = 0; k < 45; ++k) acc[k] = 0.f;

    for (int m = s * 64 + lane; m < MPTS; m += 64 * SPLIT) {
        const int i = m / NH;
        const int base = m + 2 * i;          // i*PH + (m - i*NH), PH-NH==2
        if (wid == 0) {
            float lv[9];
#pragma unroll
            for (int y = 0; y < 3; ++y)
#pragma unroll
                for (int x = 0; x < 3; ++x)
                    lv[y * 3 + x] = (float)la[base + y * PH + x] - ml[y * 3 + x];
            int k = 0;
#pragma unroll
            for (int d = 0; d < 9; ++d)
#pragma unroll
                for (int e = d; e < 9; ++e) { acc[k++] += lv[d] * lv[e]; }
        } else if (wid == 1) {
            float pv[9];
#pragma unroll
            for (int y = 0; y < 3; ++y)
#pragma unroll
                for (int x = 0; x < 3; ++x)
                    pv[y * 3 + x] = pr[base + y * PH + x] - mp[y * 3 + x];
            int k = 0;
#pragma unroll
            for (int d = 0; d < 9; ++d)
#pragma unroll
                for (int e = d; e < 9; ++e) { acc[k++] += pv[d] * pv[e]; }
        } else if (wid == 2) {
            float lv[4], pv[9];
#pragma unroll
            for (int d = 0; d < 4; ++d)
                lv[d] = (float)la[base + (d / 3) * PH + (d % 3)] - ml[d];
#pragma unroll
            for (int y = 0; y < 3; ++y)
#pragma unroll
                for (int x = 0; x < 3; ++x)
                    pv[y * 3 + x] = pr[base + y * PH + x] - mp[y * 3 + x];
#pragma unroll
            for (int d = 0; d < 4; ++d)
#pragma unroll
                for (int e = 0; e < 9; ++e) acc[d * 9 + e] += lv[d] * pv[e];
        } else {
            float lv[5], pv[9];
#pragma unroll
            for (int d = 4; d < 9; ++d)
                lv[d - 4] = (float)la[base + (d / 3) * PH + (d % 3)] - ml[d];
#pragma unroll
            for (int y = 0; y < 3; ++y)
#pragma unroll
                for (int x = 0; x < 3; ++x)
                    pv[y * 3 + x] = pr[base + y * PH + x] - mp[y * 3 + x];
#pragma unroll
            for (int d = 0; d < 5; ++d)
#pragma unroll
                for (int e = 0; e < 9; ++e) acc[d * 9 + e] += lv[d] * pv[e];
        }
    }

    // per-wave shuffle reduce: FIXED 45-iteration unroll (static acc[k]);
    // wid==2 only owns 36 outputs -> mask the atomic, not the loop.
    const int obase = (wid == 0) ? 0 : (wid == 1) ? 45 : (wid == 2) ? 90 : 126;
#pragma unroll
    for (int k = 0; k < 45; ++k) {
        const float v = wave_red(acc[k]);
        if (lane == 0 && (wid != 2 || k < 36))
            atomicAdd(covbuf + nc * 171 + obase + k, v);
    }
}

// =====================================================================
// Kernel 3: per-(n,c) 9x9 SPD math, one thread each (fully unrolled so
// all triangular arrays stay in registers), block reduce, final combine.
//   P = pp + aI = L L^T ;  Y = L^{-1} B^T ;  V = ll - Y^T Y + aI
//   rmi = 0.5 * logdet(V) = sum(log(chol(V).diag))
// =====================================================================
__global__ __launch_bounds__(128, 1) void final_kernel(
    const float* __restrict__ covbuf, const double* __restrict__ bce_part,
    const double* __restrict__ valid_part, float* __restrict__ out)
{
    const int t = threadIdx.x;
    float rmi = 0.f;
    if (t < NC) {
        const float* cb = covbuf + t * 171;

        // --- Cholesky of P = pp + alpha*I (pp stored upper-order at cb[45..89]) ---
        float L[45], dinv[9];
#pragma unroll
        for (int k = 0; k < 9; ++k) {
            float s = cb[45 + KU(k, k)] + ALPHA;
#pragma unroll
            for (int p = 0; p < k; ++p) s -= L[IDX(k, p)] * L[IDX(k, p)];
            const float dk = sqrtf(s);
            L[IDX(k, k)] = dk;
            dinv[k] = 1.f / dk;
#pragma unroll
            for (int i = k + 1; i < 9; ++i) {
                float t2 = cb[45 + KU(k, i)];
#pragma unroll
                for (int p = 0; p < k; ++p) t2 -= L[IDX(i, p)] * L[IDX(k, p)];
                L[IDX(i, k)] = t2 * dinv[k];
            }
        }

        // --- forward substitution: Y = L^{-1} B^T, B[d][e]=lp[d*9+e] at cb[90..170] ---
        float Yv[81];
#pragma unroll
        for (int i = 0; i < 9; ++i)
#pragma unroll
            for (int j = 0; j < 9; ++j) Yv[i * 9 + j] = cb[90 + j * 9 + i];  // B^T
#pragma unroll
        for (int i = 0; i < 9; ++i)
#pragma unroll
            for (int j = 0; j < 9; ++j) {
                float t2 = Yv[i * 9 + j];
#pragma unroll
                for (int p = 0; p < i; ++p) t2 -= L[IDX(i, p)] * Yv[p * 9 + j];
                Yv[i * 9 + j] = t2 * dinv[i];
            }

        // --- V = ll - Y^T Y (upper-order), then Cholesky + logdet ---
        float V[45];
#pragma unroll
        for (int d = 0; d < 9; ++d)
#pragma unroll
            for (int e = d; e < 9; ++e) {
                float s = cb[KU(d, e)];
#pragma unroll
                for (int i = 0; i < 9; ++i) s -= Yv[i * 9 + d] * Yv[i * 9 + e];
                V[KU(d, e)] = s;
            }
        float M2[45];
        float rmi_acc = 0.f;
#pragma unroll
        for (int k = 0; k < 9; ++k) {
            float s = V[KU(k, k)] + ALPHA;
#pragma unroll
            for (int p = 0; p < k; ++p) s -= M2[IDX(k, p)] * M2[IDX(k, p)];
            const float dk = sqrtf(s);
            M2[IDX(k, k)] = dk;
            rmi_acc += logf(dk);
            const float di = 1.f / dk;
#pragma unroll
            for (int i = k + 1; i < 9; ++i) {
                float t2 = V[KU(k, i)];
#pragma unroll
                for (int p = 0; p < k; ++p) t2 -= M2[IDX(i, p)] * M2[IDX(k, p)];
                M2[IDX(i, k)] = t2 * di;
            }
        }
        rmi = rmi_acc;  // = 0.5 * logdet
    }

    __shared__ float red[128];
    red[t] = rmi;
    __syncthreads();
#pragma unroll
    for (int off = 64; off >= 1; off >>= 1) {
        if (t < off) red[t] += red[t + off];
        __syncthreads();
    }
    if (t == 0) {
        double b = 0.0, v = 0.0;
        for (int k = 0; k < 64; ++k) { b += bce_part[k]; v += valid_part[k]; }
        const float bce_loss = (float)(b / (v + 1.0));
        const float rmi_loss = red[0] / (float)(NBATCH * 9);   // mean over N, /HALF_D, sum over C
        out[0] = 0.5f * bce_loss + 0.5f * rmi_loss;
    }
}

// =====================================================================
extern "C" void kernel_launch(void* const* d_in, const int* in_sizes, int n_in,
                              void* d_out, int out_size, void* d_ws, size_t ws_size,
                              hipStream_t stream)
{
    const float* logits = (const float*)d_in[0];
    const int*   labels = (const int*)d_in[1];
    char* ws = (char*)d_ws;

    double*        bce_part   = (double*)(ws + OFF_BCE);
    double*        valid_part = (double*)(ws + OFF_VALID);
    float*         meansums   = (float*)(ws + OFF_MEANS);
    float*         covbuf     = (float*)(ws + OFF_COV);
    unsigned char* la_pool    = (unsigned char*)(ws + OFF_LA8);
    float*         pr_pool    = (float*)(ws + OFF_PR);

    hipMemsetAsync(ws, 0, ZERO_BYTES, stream);

    dim3 g1((PLANE + 255) / 256, NCLS, NBATCH);
    pool_bce_kernel<<<g1, 256, 0, stream>>>(logits, labels, la_pool, pr_pool,
                                            meansums, bce_part, valid_part);
    cov_kernel<<<NC * SPLIT, 256, 0, stream>>>(la_pool, pr_pool, meansums, covbuf);
    final_kernel<<<1, 128, 0, stream>>>(covbuf, bce_part, valid_part, (float*)d_out);
}